// Round 8
// baseline (199.114 us; speedup 1.0000x reference)
//
#include <hip/hip_runtime.h>
#include <cstdint>
#include <cstddef>

// SLSTM cell, B=4096 IN=1024 HID=2048 GATE=8192, NH=8 HS=256.
// v8: main rebuilt m97-style for occupancy: 256 thr, tile 64r x 64j x 4g,
// BK=32, 40KB dbuf LDS, acc 4x4, ~110 VGPR -> 4 blocks/CU. Full unroll,
// WAITV(0)+BAR per step (drains hidden by 4-block co-residency). 2-bit chunk
// swizzle (c ^= (slot>>1)&3) => 2-way banks at BK32. hproj/casts/pack = v7.

typedef unsigned short u16;
typedef unsigned int   u32;
typedef __bf16 bf16x8 __attribute__((ext_vector_type(8)));
typedef float  f32x4  __attribute__((ext_vector_type(4)));

__device__ __forceinline__ u16 f2bf(float f) {
  u32 u = __builtin_bit_cast(u32, f);
  u32 r = (u + 0x7fffu + ((u >> 16) & 1u)) >> 16;   // RNE
  return (u16)r;
}
__device__ __forceinline__ float bf2f(u16 v) {
  u32 u = ((u32)v) << 16;
  return __builtin_bit_cast(float, u);
}
__device__ __forceinline__ void gll16(const void* g, void* l) {
  __builtin_amdgcn_global_load_lds(
      (__attribute__((address_space(1))) void*)(uintptr_t)g,
      (__attribute__((address_space(3))) void*)l, 16, 0, 0);
}

#define BAR() asm volatile("s_barrier" ::: "memory")
#define WAITV(N) asm volatile("s_waitcnt vmcnt(" #N ")" ::: "memory")

// ---------------- cast f32 -> bf16, 8 elems/thread ----------------
__global__ void cast_bf16_kernel(const float* __restrict__ src, u16* __restrict__ dst, int n8) {
  int i = blockIdx.x * blockDim.x + threadIdx.x;
  if (i >= n8) return;
  const float4* s = reinterpret_cast<const float4*>(src) + (size_t)i * 2;
  float4 a = s[0], b = s[1];
  union { u16 h[8]; uint4 v; } o;
  o.h[0] = f2bf(a.x); o.h[1] = f2bf(a.y); o.h[2] = f2bf(a.z); o.h[3] = f2bf(a.w);
  o.h[4] = f2bf(b.x); o.h[5] = f2bf(b.y); o.h[6] = f2bf(b.z); o.h[7] = f2bf(b.w);
  reinterpret_cast<uint4*>(dst)[i] = o.v;
}

// ---------------- pack W transposed: WpackT[g][r], g<8192, r<1280 ----------------
__global__ void pack_w_kernel(const float* __restrict__ Wi, const float* __restrict__ Wh,
                              u16* __restrict__ Wt) {
  __shared__ u16 tile[64][65];
  const int g0 = blockIdx.x * 64;
  const int r0 = blockIdx.y * 64;
  const int tx = threadIdx.x;
  const int ty = threadIdx.y;
  #pragma unroll
  for (int i = 0; i < 4; ++i) {
    const int rr = ty + 16 * i;
    const int r = r0 + rr;
    const int g = g0 + tx;
    float v;
    if (r < 1024) v = Wi[(size_t)r * 8192 + g];
    else {
      const int head = g >> 10;
      v = Wh[(size_t)(head * 256 + (r - 1024)) * 1024 + (g & 1023)];
    }
    tile[rr][tx] = f2bf(v);
  }
  __syncthreads();
  #pragma unroll
  for (int i = 0; i < 4; ++i) {
    const int gg = ty + 16 * i;
    Wt[(size_t)(g0 + gg) * 1280 + r0 + tx] = tile[tx][gg];
  }
}

// ---------------- hproj (v7, proven): hp[b][g] = sum_k h[b,head*256+k] Wt[g][1024+k]
__global__ __launch_bounds__(512, 2) void hproj_kernel(
    const u16* __restrict__ hb, const u16* __restrict__ Wt, u16* __restrict__ hp)
{
  extern __shared__ __align__(16) u16 lds[];
  const int tid = threadIdx.x, lane = tid & 63, w = tid >> 6;
  const int wr = w >> 2, wc = w & 3;
  const int d = blockIdx.x;
  const int xcd = d & 7, loc = d >> 3;
  const int rb = (xcd & 3) * 8 + (loc & 7);
  const int cb = (xcd >> 2) * 32 + (loc >> 3);
  const int row0 = rb * 128;
  const int g0 = cb * 128;
  const int head = cb >> 3;
  const int l15 = lane & 15, l4 = lane >> 4;
  const int sl0 = (l4 ^ (l15 & 7)) * 8;
  const int sl1 = ((4 + l4) ^ (l15 & 7)) * 8;

  const int u0 = tid, u1 = 512 + tid;
  const int r0u = u0 >> 3, r1u = u1 >> 3;
  const int kc0 = (u0 & 7) ^ (r0u & 7), kc1 = (u1 & 7) ^ (r1u & 7);
  const int d0 = u0 * 8, d1 = u1 * 8;
  const size_t aS0 = (size_t)(row0 + r0u) * 2048 + head * 256 + kc0 * 8;
  const size_t aS1 = (size_t)(row0 + r1u) * 2048 + head * 256 + kc1 * 8;
  const size_t bS0 = (size_t)(g0 + r0u) * 1280 + 1024 + kc0 * 8;
  const size_t bS1 = (size_t)(g0 + r1u) * 1280 + 1024 + kc1 * 8;

  const int aRd = (wr * 64 + l15) * 64;
  const int bRd = (wc * 32 + l15) * 64;

  f32x4 acc[2][4];
  #pragma unroll
  for (int q = 0; q < 2; ++q)
    #pragma unroll
    for (int f = 0; f < 4; ++f)
      acc[q][f] = f32x4{0.0f, 0.0f, 0.0f, 0.0f};

#define HST(T, NB) do { \
    gll16(hb + aS0 + (size_t)(T) * 64, lds + (NB) * 8192 + d0); \
    gll16(hb + aS1 + (size_t)(T) * 64, lds + (NB) * 8192 + d1); \
    gll16(Wt + bS0 + (size_t)(T) * 64, lds + 16384 + (NB) * 8192 + d0); \
    gll16(Wt + bS1 + (size_t)(T) * 64, lds + 16384 + (NB) * 8192 + d1); } while (0)

  HST(0, 0);
  WAITV(0); BAR();

  #pragma unroll
  for (int t = 0; t < 4; ++t) {
    const int buf = t & 1;
    bf16x8 av[4][2], bv[2][2];
    #pragma unroll
    for (int f = 0; f < 4; ++f) {
      const u16* p = lds + buf * 8192 + aRd + f * 1024;
      av[f][0] = *(const bf16x8*)(p + sl0);
      av[f][1] = *(const bf16x8*)(p + sl1);
    }
    #pragma unroll
    for (int q = 0; q < 2; ++q) {
      const u16* p = lds + 16384 + buf * 8192 + bRd + q * 1024;
      bv[q][0] = *(const bf16x8*)(p + sl0);
      bv[q][1] = *(const bf16x8*)(p + sl1);
    }
    if (t < 3) HST(t + 1, buf ^ 1);
    __builtin_amdgcn_s_setprio(1);
    #pragma unroll
    for (int q = 0; q < 2; ++q)
      #pragma unroll
      for (int f = 0; f < 4; ++f)
        #pragma unroll
        for (int k = 0; k < 2; ++k)
          acc[q][f] = __builtin_amdgcn_mfma_f32_16x16x32_bf16(av[f][k], bv[q][k], acc[q][f], 0, 0, 0);
    __builtin_amdgcn_s_setprio(0);
    if (t < 3) { WAITV(0); BAR(); }
  }

  #pragma unroll
  for (int q = 0; q < 2; ++q)
    #pragma unroll
    for (int f = 0; f < 4; ++f)
      #pragma unroll
      for (int r = 0; r < 4; ++r) {
        const int row = row0 + wr * 64 + f * 16 + l4 * 4 + r;
        const int g = g0 + wc * 32 + q * 16 + l15;
        hp[(size_t)row * 8192 + g] = f2bf(acc[q][f][r]);
      }
#undef HST
}

// ---------------- main v8: 64r x 64j x 4g tile, BK=32, 4 blocks/CU ----------------
// LDS (u16): A[2] @ 0/2048 (64x32), B[2] @ 4096/12288 (256x32). 20480 u16 = 40KB.
// Epilogue chunks overlay: ebuf[2] @ 0/10240 (c 0 | m 2048 | n 4096 | hp 6144..10240).
__global__ __launch_bounds__(256, 4) void slstm_main(
    const u16* __restrict__ xb, const u16* __restrict__ Wt, const u16* __restrict__ hp,
    const float* __restrict__ b_i, const float* __restrict__ b_h,
    const float* __restrict__ c_in, const float* __restrict__ m_in, const float* __restrict__ n_in,
    float* __restrict__ out)
{
  extern __shared__ __align__(16) u16 lds[];
  const int tid = threadIdx.x, lane = tid & 63, w = tid >> 6;   // w = j-slice 0..3
  const int l15 = lane & 15, l4 = lane >> 4;

  // per-XCD: 4 j-panels x 64 row-blocks (B panel 2MB -> L2-hot)
  const int d = blockIdx.x;
  const int xcd = d & 7, loc = d >> 3;          // loc 0..255
  const int jb = xcd * 4 + (loc >> 6);          // 0..31
  const int rb = loc & 63;                      // 0..63
  const int row0 = rb * 64;
  const int j0 = jb * 64;

  // fragment read offsets (swizzle s(slot) = (slot>>1)&3; uniform across f/q)
  const int aslot = l15;                        // row slot base (f*16 doesn't change s)
  const int aRd0 = aslot * 32 + ((l4 ^ ((aslot >> 1) & 3)) << 3);       // + f*512
  const int bslot = w * 16 + l15;               // col slot base (q*64 doesn't change s)
  const int bRd0 = bslot * 32 + ((l4 ^ ((bslot >> 1) & 3)) << 3);       // + q*2048

  // staging (linear LDS dest, pre-swizzled global source)
  const int ar = tid >> 2, ac = tid & 3;
  const int acs = ac ^ ((ar >> 1) & 3);
  const u16* aSrc = xb + (size_t)(row0 + ar) * 1024 + acs * 8;          // + t*32
  const int aDstU = tid * 8;
  const int bc = tid >> 2;                      // jj 0..63 (q = i)
  const int bcs = ac ^ ((bc >> 1) & 3);         // (i*64 doesn't change s bits)
  const u16* bSrc0 = Wt + (size_t)(j0 + bc) * 1280 + bcs * 8;           // + i*2048*1280 + t*32

  f32x4 acc[4][4];
  #pragma unroll
  for (int q = 0; q < 4; ++q)
    #pragma unroll
    for (int f = 0; f < 4; ++f)
      acc[q][f] = f32x4{0.0f, 0.0f, 0.0f, 0.0f};

#define STG(T) do { const int p_ = (T) & 1; \
    gll16(aSrc + (size_t)(T) * 32, lds + p_ * 2048 + aDstU); \
    _Pragma("unroll") for (int i_ = 0; i_ < 4; ++i_) \
      gll16(bSrc0 + (size_t)i_ * 2621440 + (size_t)(T) * 32, \
            lds + 4096 + p_ * 8192 + i_ * 2048 + aDstU); } while (0)

  STG(0);
  WAITV(0); BAR();
  #pragma unroll
  for (int t = 0; t < 32; ++t) {
    if (t < 31) STG(t + 1);
    const int p = t & 1;
    bf16x8 av[4], bv[4];
    #pragma unroll
    for (int f = 0; f < 4; ++f)
      av[f] = *(const bf16x8*)(lds + p * 2048 + aRd0 + f * 512);
    #pragma unroll
    for (int q = 0; q < 4; ++q)
      bv[q] = *(const bf16x8*)(lds + 4096 + p * 8192 + bRd0 + q * 2048);
    __builtin_amdgcn_s_setprio(1);
    #pragma unroll
    for (int q = 0; q < 4; ++q)
      #pragma unroll
      for (int f = 0; f < 4; ++f)
        acc[q][f] = __builtin_amdgcn_mfma_f32_16x16x32_bf16(av[f], bv[q], acc[q][f], 0, 0, 0);
    __builtin_amdgcn_s_setprio(0);
    WAITV(0); BAR();
  }

  // ---- epilogue (constants computed post-loop to keep K-loop VGPR low) ----
  const int gj = j0 + w * 16 + l15;
  const float bias0 = b_i[gj]        + b_h[gj];
  const float bias1 = b_i[2048 + gj] + b_h[2048 + gj];
  const float bias2 = b_i[4096 + gj] + b_h[4096 + gj];
  const float bias3 = b_i[6144 + gj] + b_h[6144 + gj];

  const int er = tid >> 4, ec4 = (tid & 15) * 4;                 // cmn: row, col*4
  const size_t eCsrc = (size_t)(row0 + er) * 2048 + j0 + ec4;    // + k*32768 (f32)
  const int eCdstU = tid * 8;
  // hp: units tid and 256+tid -> row=u>>5, seg=u&31 -> q=seg>>3, jj8=(seg&7)*8
  const int hr0 = tid >> 5, hs0 = tid & 31;
  const int hr1 = (256 + tid) >> 5, hs1 = tid & 31;              // (256+tid)&31 == tid&31
  const size_t hSrc0 = (size_t)(row0 + hr0) * 8192 + (hs0 >> 3) * 2048 + j0 + (hs0 & 7) * 8;
  const size_t hSrc1 = (size_t)(row0 + hr1) * 8192 + (hs1 >> 3) * 2048 + j0 + (hs1 & 7) * 8;
  const int hDst0 = 6144 + tid * 8, hDst1 = 6144 + (256 + tid) * 8;

#define EST(K) do { const int p_ = (K) & 1; u16* eb_ = lds + p_ * 10240; \
    gll16(c_in + eCsrc + (size_t)(K) * 32768, eb_ + eCdstU); \
    gll16(m_in + eCsrc + (size_t)(K) * 32768, eb_ + 2048 + eCdstU); \
    gll16(n_in + eCsrc + (size_t)(K) * 32768, eb_ + 4096 + eCdstU); \
    gll16(hp + hSrc0 + (size_t)(K) * 131072, eb_ + hDst0); \
    gll16(hp + hSrc1 + (size_t)(K) * 131072, eb_ + hDst1); } while (0)

#define ECOMP(K) do { const int p_ = (K) & 1; \
    const float* pc_ = (const float*)(lds + p_ * 10240); \
    const u16* ph_ = lds + p_ * 10240 + 6144; \
    _Pragma("unroll") for (int r_ = 0; r_ < 4; ++r_) { \
      const int rl_ = l4 * 4 + r_; \
      const int ci_ = rl_ * 64 + w * 16 + l15; \
      const int hi_ = rl_ * 256 + w * 16 + l15; \
      const float cv = pc_[ci_], mv = pc_[1024 + ci_], nv = pc_[2048 + ci_]; \
      const float it = acc[0][K][r_] + bias0 + bf2f(ph_[hi_]); \
      const float ft = acc[1][K][r_] + bias1 + bf2f(ph_[64 + hi_]); \
      const float zt = acc[2][K][r_] + bias2 + bf2f(ph_[128 + hi_]); \
      const float ot = acc[3][K][r_] + bias3 + bf2f(ph_[192 + hi_]); \
      const float mn = fmaxf(ft + mv, it); \
      const float iv = __expf(it - mn); \
      const float fv = __expf(ft - mn + mv); \
      const float az = fabsf(zt); \
      const float e2 = __expf(-2.0f * az); \
      const float tz = (1.0f - e2) / (1.0f + e2); \
      const float zv = (zt >= 0.0f) ? tz : -tz; \
      const float ov = 1.0f / (1.0f + __expf(-ot)); \
      const float cn = fv * cv + iv * zv; \
      const float nn = fv * nv + iv; \
      const float hn = ov * (cn / nn); \
      const size_t idx = (size_t)(row0 + (K) * 16 + rl_) * 2048 + gj; \
      out[idx]            = hn; \
      out[ 8388608 + idx] = cn; \
      out[16777216 + idx] = mn; \
      out[25165824 + idx] = nn; \
    } } while (0)

  EST(0);
  WAITV(0); BAR();
  #pragma unroll
  for (int k = 0; k < 4; ++k) {
    if (k < 3) EST(k + 1);
    ECOMP(k);
    if (k < 3) { WAITV(0); BAR(); }
  }
#undef STG
#undef EST
#undef ECOMP
}

extern "C" void kernel_launch(void* const* d_in, const int* in_sizes, int n_in,
                              void* d_out, int out_size, void* d_ws, size_t ws_size,
                              hipStream_t stream) {
  (void)in_sizes; (void)n_in; (void)out_size; (void)ws_size;
  const float* x  = (const float*)d_in[0];
  const float* h  = (const float*)d_in[1];
  const float* c  = (const float*)d_in[2];
  const float* m  = (const float*)d_in[3];
  const float* n  = (const float*)d_in[4];
  const float* Wi = (const float*)d_in[5];
  const float* bi = (const float*)d_in[6];
  const float* Wh = (const float*)d_in[7];
  const float* bh = (const float*)d_in[8];
  float* out = (float*)d_out;

  // workspace (bf16): Wt 8192x1280 | xb 4096x1024 | hb 4096x2048 | hp 4096x8192
  u16* Wt = (u16*)d_ws;
  u16* xb = Wt + (size_t)8192 * 1280;
  u16* hb = xb + (size_t)4096 * 1024;
  u16* hp = hb + (size_t)4096 * 2048;

  hipFuncSetAttribute((const void*)hproj_kernel,
                      hipFuncAttributeMaxDynamicSharedMemorySize, 65536);
  hipFuncSetAttribute((const void*)slstm_main,
                      hipFuncAttributeMaxDynamicSharedMemorySize, 40960);

  cast_bf16_kernel<<<2048, 256, 0, stream>>>(x, xb, 4096 * 1024 / 8);
  cast_bf16_kernel<<<4096, 256, 0, stream>>>(h, hb, 4096 * 2048 / 8);
  pack_w_kernel<<<dim3(128, 20), dim3(64, 16), 0, stream>>>(Wi, Wh, Wt);
  hproj_kernel<<<2048, 512, 65536, stream>>>(hb, Wt, hp);
  slstm_main<<<2048, 256, 40960, stream>>>(xb, Wt, hp, bi, bh, c, m, n, out);
}

// Round 9
// 183.261 us; speedup vs baseline: 1.0865x; 1.0865x over previous
//
#include <hip/hip_runtime.h>
#include <cstdint>
#include <cstddef>

// SLSTM cell, B=4096 IN=1024 HID=2048 GATE=8192, NH=8 HS=256.
// v10: main = v6 verbatim (proven 118us). hproj rewritten stage-all: 128x128
// tile x full K=256 in LDS (128KB), ONE drain+barrier, 64 MFMA/wave, slab
// layout with 2-bit XOR swizzle. prep unchanged (at BW floor).

typedef unsigned short u16;
typedef unsigned int   u32;
typedef __bf16 bf16x8 __attribute__((ext_vector_type(8)));
typedef float  f32x4  __attribute__((ext_vector_type(4)));

__device__ __forceinline__ u16 f2bf(float f) {
  u32 u = __builtin_bit_cast(u32, f);
  u32 r = (u + 0x7fffu + ((u >> 16) & 1u)) >> 16;   // RNE
  return (u16)r;
}
__device__ __forceinline__ float bf2f(u16 v) {
  u32 u = ((u32)v) << 16;
  return __builtin_bit_cast(float, u);
}
__device__ __forceinline__ void gll16(const void* g, void* l) {
  __builtin_amdgcn_global_load_lds(
      (__attribute__((address_space(1))) void*)(uintptr_t)g,
      (__attribute__((address_space(3))) void*)l, 16, 0, 0);
}

#define BAR() asm volatile("s_barrier" ::: "memory")
#define WAITV(N) asm volatile("s_waitcnt vmcnt(" #N ")" ::: "memory")

// ---------------- cast f32 -> bf16, 8 elems/thread ----------------
__global__ void cast_bf16_kernel(const float* __restrict__ src, u16* __restrict__ dst, int n8) {
  int i = blockIdx.x * blockDim.x + threadIdx.x;
  if (i >= n8) return;
  const float4* s = reinterpret_cast<const float4*>(src) + (size_t)i * 2;
  float4 a = s[0], b = s[1];
  union { u16 h[8]; uint4 v; } o;
  o.h[0] = f2bf(a.x); o.h[1] = f2bf(a.y); o.h[2] = f2bf(a.z); o.h[3] = f2bf(a.w);
  o.h[4] = f2bf(b.x); o.h[5] = f2bf(b.y); o.h[6] = f2bf(b.z); o.h[7] = f2bf(b.w);
  reinterpret_cast<uint4*>(dst)[i] = o.v;
}

// ---------------- pack W transposed: WpackT[g][r], g<8192, r<1280 ----------------
__global__ void pack_w_kernel(const float* __restrict__ Wi, const float* __restrict__ Wh,
                              u16* __restrict__ Wt) {
  __shared__ u16 tile[64][65];
  const int g0 = blockIdx.x * 64;
  const int r0 = blockIdx.y * 64;
  const int tx = threadIdx.x;
  const int ty = threadIdx.y;
  #pragma unroll
  for (int i = 0; i < 4; ++i) {
    const int rr = ty + 16 * i;
    const int r = r0 + rr;
    const int g = g0 + tx;
    float v;
    if (r < 1024) v = Wi[(size_t)r * 8192 + g];
    else {
      const int head = g >> 10;
      v = Wh[(size_t)(head * 256 + (r - 1024)) * 1024 + (g & 1023)];
    }
    tile[rr][tx] = f2bf(v);
  }
  __syncthreads();
  #pragma unroll
  for (int i = 0; i < 4; ++i) {
    const int gg = ty + 16 * i;
    Wt[(size_t)(g0 + gg) * 1280 + r0 + tx] = tile[tx][gg];
  }
}

// ---------------- hproj v10: stage-all K=256, one drain ----------------
// 128x128 tile, grid 2048 (32 rb x 64 cb), 512 thr (8 waves: wr 0..1, wc 0..3).
// LDS (u16): A slab kk at kk*4096 (row*32+ch*8), kk 0..7; B at 32768 + same.
__global__ __launch_bounds__(512, 1) void hproj_kernel(
    const u16* __restrict__ hb, const u16* __restrict__ Wt, u16* __restrict__ hp)
{
  extern __shared__ __align__(16) u16 lds[];
  const int tid = threadIdx.x, lane = tid & 63, w = tid >> 6;
  const int wr = w >> 2, wc = w & 3;
  const int d = blockIdx.x;
  const int xcd = d & 7, loc = d >> 3;
  const int rb = (xcd & 3) * 8 + (loc & 7);     // 0..31
  const int cb = (xcd >> 2) * 32 + (loc >> 3);  // 0..63
  const int row0 = rb * 128;
  const int g0 = cb * 128;
  const int head = cb >> 3;
  const int l15 = lane & 15, l4 = lane >> 4;
  const int sw = (l4 ^ ((l15 >> 1) & 3)) << 3;  // swizzled chunk offset (u16)

  // ---- stage everything: 8 A units + 8 B units per thread ----
  #pragma unroll
  for (int i = 0; i < 8; ++i) {
    const int u = i * 512 + tid;
    const int kk = u >> 9, rem = u & 511;
    const int row = rem >> 2, ch = rem & 3;
    const int chs = ch ^ ((row >> 1) & 3);
    gll16(hb + (size_t)(row0 + row) * 2048 + head * 256 + kk * 32 + chs * 8,
          lds + u * 8);
    gll16(Wt + (size_t)(g0 + row) * 1280 + 1024 + kk * 32 + chs * 8,
          lds + 32768 + u * 8);
  }
  WAITV(0); BAR();

  f32x4 acc[2][4];
  #pragma unroll
  for (int q = 0; q < 2; ++q)
    #pragma unroll
    for (int f = 0; f < 4; ++f)
      acc[q][f] = f32x4{0.0f, 0.0f, 0.0f, 0.0f};

  #pragma unroll
  for (int kk = 0; kk < 8; ++kk) {
    bf16x8 av[4], bv[2];
    #pragma unroll
    for (int f = 0; f < 4; ++f)
      av[f] = *(const bf16x8*)(lds + kk * 4096 + (wr * 64 + f * 16 + l15) * 32 + sw);
    #pragma unroll
    for (int q = 0; q < 2; ++q)
      bv[q] = *(const bf16x8*)(lds + 32768 + kk * 4096 + (wc * 32 + q * 16 + l15) * 32 + sw);
    #pragma unroll
    for (int q = 0; q < 2; ++q)
      #pragma unroll
      for (int f = 0; f < 4; ++f)
        acc[q][f] = __builtin_amdgcn_mfma_f32_16x16x32_bf16(av[f], bv[q], acc[q][f], 0, 0, 0);
  }

  // epilogue: store hp bf16 (same mapping as proven v7)
  #pragma unroll
  for (int q = 0; q < 2; ++q)
    #pragma unroll
    for (int f = 0; f < 4; ++f)
      #pragma unroll
      for (int r = 0; r < 4; ++r) {
        const int row = row0 + wr * 64 + f * 16 + l4 * 4 + r;
        const int g = g0 + wc * 32 + q * 16 + l15;
        hp[(size_t)row * 8192 + g] = f2bf(acc[q][f][r]);
      }
}

// ---------------- main: x-GEMM (K=1024) + gates, hp added in epilogue (v6 verbatim) ----
__global__ __launch_bounds__(512, 2) void slstm_main(
    const u16* __restrict__ xb, const u16* __restrict__ Wt, const u16* __restrict__ hp,
    const float* __restrict__ b_i, const float* __restrict__ b_h,
    const float* __restrict__ c_in, const float* __restrict__ m_in, const float* __restrict__ n_in,
    float* __restrict__ out)
{
  extern __shared__ __align__(16) u16 lds[];
  const int tid = threadIdx.x, lane = tid & 63, w = tid >> 6;
  const int wr = w >> 2, wj = w & 3;
  const int d = blockIdx.x;
  const int xcd = d & 7, loc = d >> 3;
  const int row_blk = (xcd & 3) * 4 + (loc & 3);   // 0..15
  const int j_blk   = (xcd >> 2) * 16 + (loc >> 2);// 0..31
  const int row0 = row_blk * 256;
  const int j0   = j_blk * 64;
  const int l15 = lane & 15, l4 = lane >> 4;
  const int sl0 = (l4 ^ (l15 & 7)) * 8;
  const int sl1 = ((4 + l4) ^ (l15 & 7)) * 8;
  const int aBase = l15 * 64;
  const int bBase = wj * 1024 + l15 * 64;

  // biases first; drain before ledger starts
  const int gj = j0 + wj * 16 + l15;
  const float bias0 = b_i[gj]        + b_h[gj];
  const float bias1 = b_i[2048 + gj] + b_h[2048 + gj];
  const float bias2 = b_i[4096 + gj] + b_h[4096 + gj];
  const float bias3 = b_i[6144 + gj] + b_h[6144 + gj];
  WAITV(0);

  const int u0 = tid, u1 = 512 + tid;
  const int r0u = u0 >> 3, r1u = u1 >> 3;
  const int kc0 = (u0 & 7) ^ (r0u & 7), kc1 = (u1 & 7) ^ (r1u & 7);
  const int d0 = u0 * 8, d1 = u1 * 8;
  const size_t aL0 = (size_t)(row0 + r0u) * 1024 + kc0 * 8;
  const size_t aL1 = (size_t)(row0 + r1u) * 1024 + kc1 * 8;
  const int gL0 = (r0u >> 6) * 2048 + j0 + (r0u & 63);
  const int gL1 = (r1u >> 6) * 2048 + j0 + (r1u & 63);
  const size_t bL0 = (size_t)gL0 * 1280 + kc0 * 8;
  const size_t bL1 = (size_t)gL1 * 1280 + kc1 * 8;
  const size_t bH0 = bL0 + (size_t)2 * 2048 * 1280;
  const size_t bH1 = bL1 + (size_t)2 * 2048 * 1280;

  f32x4 acc[4][8];
  #pragma unroll
  for (int q = 0; q < 4; ++q)
    #pragma unroll
    for (int f = 0; f < 8; ++f)
      acc[q][f] = f32x4{0.0f, 0.0f, 0.0f, 0.0f};

  // epilogue staging constants
  const int esStripe = tid >> 8, esRowq = (tid >> 4) & 15, esCol16 = tid & 15;
  const size_t esC0 = (size_t)(row0 + esStripe * 128 + esRowq) * 2048 + j0 + esCol16 * 4;
  const int hu0 = tid, hu1 = 512 + tid;
  const size_t esH0 = (size_t)(row0 + ((hu0 >> 7) & 1) * 128 + ((hu0 >> 3) & 15)) * 8192
                      + (hu0 >> 8) * 2048 + j0 + (hu0 & 7) * 8;
  const size_t esH1 = (size_t)(row0 + ((hu1 >> 7) & 1) * 128 + ((hu1 >> 3) & 15)) * 8192
                      + (hu1 >> 8) * 2048 + j0 + (hu1 & 7) * 8;
  const int dH0 = hu0 * 8, dH1 = hu1 * 8;
  const int dC = tid * 8;

#define X_ALO(T, NB) do { gll16(xb + aL0 + (size_t)(T)*64, lds + (NB)*16384 + d0); \
                          gll16(xb + aL1 + (size_t)(T)*64, lds + (NB)*16384 + d1); } while(0)
#define X_AHI(T, NB) do { gll16(xb + aL0 + (size_t)128*1024 + (size_t)(T)*64, lds + (NB)*16384 + 8192 + d0); \
                          gll16(xb + aL1 + (size_t)128*1024 + (size_t)(T)*64, lds + (NB)*16384 + 8192 + d1); } while(0)
#define X_BLO(T, NB) do { gll16(Wt + bL0 + (size_t)(T)*64, lds + 32768 + (NB)*16384 + d0); \
                          gll16(Wt + bL1 + (size_t)(T)*64, lds + 32768 + (NB)*16384 + d1); } while(0)
#define X_BHI(T, NB) do { gll16(Wt + bH0 + (size_t)(T)*64, lds + 32768 + (NB)*16384 + 8192 + d0); \
                          gll16(Wt + bH1 + (size_t)(T)*64, lds + 32768 + (NB)*16384 + 8192 + d1); } while(0)

// A read: half = wr (rows wr*128..+128), slot-in-half = FH*64 + f_*16 + l15
#define RD_A(DST, BUF, FH) do { \
  _Pragma("unroll") for (int f_ = 0; f_ < 4; ++f_) { \
    const u16* p_ = lds + (BUF)*16384 + wr*8192 + (FH)*4096 + aBase + f_*1024; \
    DST[f_][0] = *(const bf16x8*)(p_ + sl0); \
    DST[f_][1] = *(const bf16x8*)(p_ + sl1); } } while(0)
#define RD_B(DST, BUF, QH) do { \
  _Pragma("unroll") for (int q_ = 0; q_ < 2; ++q_) { \
    const u16* p_ = lds + 32768 + (BUF)*16384 + (QH)*8192 + q_*4096 + bBase; \
    DST[q_][0] = *(const bf16x8*)(p_ + sl0); \
    DST[q_][1] = *(const bf16x8*)(p_ + sl1); } } while(0)
#define MMQ(FH, QH, AF, BF) do { \
  __builtin_amdgcn_s_setprio(1); \
  _Pragma("unroll") for (int q_ = 0; q_ < 2; ++q_) \
  _Pragma("unroll") for (int f_ = 0; f_ < 4; ++f_) \
  _Pragma("unroll") for (int k_ = 0; k_ < 2; ++k_) \
    acc[(QH)*2+q_][(FH)*4+f_] = __builtin_amdgcn_mfma_f32_16x16x32_bf16( \
        AF[f_][k_], BF[q_][k_], acc[(QH)*2+q_][(FH)*4+f_], 0, 0, 0); \
  __builtin_amdgcn_s_setprio(0); } while(0)
#define TILE(BUF, I0, W0, I1, I2, I3, W3) do { \
  bf16x8 aF[4][2], aG[4][2], bF[2][2], bG[2][2]; \
  RD_A(aF, BUF, 0); RD_B(bF, BUF, 0); \
  I0; W0; BAR(); \
  MMQ(0, 0, aF, bF); BAR(); \
  RD_B(bG, BUF, 1); \
  I1; BAR(); \
  MMQ(0, 1, aF, bG); BAR(); \
  RD_A(aG, BUF, 1); \
  I2; BAR(); \
  MMQ(1, 1, aG, bG); BAR(); \
  RD_B(bF, BUF, 0); \
  I3; W3; BAR(); \
  MMQ(1, 0, aG, bF); BAR(); } while(0)

  // ES chunk staging (parity regions overlaid on GEMM buffers):
  // p0: c@0, m@4096, n@8192 (A-buf0), hp@32768 (B-buf0)
  // p1: c@16384, m@20480, n@24576 (A-buf1), hp@49152 (B-buf1)
#define ISSUE_ES(K) do { const int p_ = (K)&1; \
  const int cb_ = p_ ? 16384 : 0; const int hb_ = p_ ? 49152 : 32768; \
  gll16(c_in + esC0 + (size_t)(K)*32768, lds + cb_ + dC); \
  gll16(m_in + esC0 + (size_t)(K)*32768, lds + cb_ + 4096 + dC); \
  gll16(n_in + esC0 + (size_t)(K)*32768, lds + cb_ + 8192 + dC); \
  gll16(hp + esH0 + (size_t)(K)*131072, lds + hb_ + dH0); \
  gll16(hp + esH1 + (size_t)(K)*131072, lds + hb_ + dH1); } while(0)
#define ES0A do { gll16(c_in + esC0, lds + dC); gll16(m_in + esC0, lds + 4096 + dC); } while(0)
#define ES0B do { gll16(n_in + esC0, lds + 8192 + dC); gll16(hp + esH0, lds + 32768 + dH0); } while(0)
#define ES0C do { gll16(hp + esH1, lds + 32768 + dH1); } while(0)

  // ---- prologue ----
  X_ALO(0, 0); X_AHI(0, 0); X_BLO(0, 0); X_BHI(0, 0);
  WAITV(2); BAR();

  // ---- tiles 0..14 ----
  for (int tt = 0; tt < 7; ++tt) {
    const int ta = 2 * tt + 1, tb = 2 * tt + 2;
    TILE(0, X_ALO(ta, 1), WAITV(2), X_AHI(ta, 1), X_BLO(ta, 1), X_BHI(ta, 1), WAITV(2));
    TILE(1, X_ALO(tb, 0), WAITV(2), X_AHI(tb, 0), X_BLO(tb, 0), X_BHI(tb, 0), WAITV(2));
  }
  TILE(0, X_ALO(15, 1), WAITV(2), X_AHI(15, 1), X_BLO(15, 1), X_BHI(15, 1), WAITV(2));
  // ---- tile 15: stage epilogue chunk 0 ----
  TILE(1, ES0A, WAITV(2), ES0B, ES0C, (void)0, WAITV(0));

  // ---- epilogue: 8 pipelined chunks (16 rows per stripe each) ----
#define ECOMP(K) do { const int p_ = (K)&1; \
  const float* pc_ = (const float*)(lds + (p_ ? 16384 : 0)); \
  const float* pm_ = pc_ + 2048; \
  const float* pn_ = pc_ + 4096; \
  const u16* ph_ = lds + (p_ ? 49152 : 32768); \
  _Pragma("unroll") for (int r_ = 0; r_ < 4; ++r_) { \
    const int fx_ = wr * 1024 + (l4 * 4 + r_) * 64 + wj * 16 + l15; \
    const float cv = pc_[fx_], mv = pm_[fx_], nv = pn_[fx_]; \
    const float it = acc[0][K][r_] + bias0 + bf2f(ph_[fx_]); \
    const float ft = acc[1][K][r_] + bias1 + bf2f(ph_[2048 + fx_]); \
    const float zt = acc[2][K][r_] + bias2 + bf2f(ph_[4096 + fx_]); \
    const float ot = acc[3][K][r_] + bias3 + bf2f(ph_[6144 + fx_]); \
    const float mn = fmaxf(ft + mv, it); \
    const float iv = __expf(it - mn); \
    const float fv = __expf(ft - mn + mv); \
    const float az = fabsf(zt); \
    const float e2 = __expf(-2.0f * az); \
    const float tz = (1.0f - e2) / (1.0f + e2); \
    const float zv = (zt >= 0.0f) ? tz : -tz; \
    const float ov = 1.0f / (1.0f + __expf(-ot)); \
    const float cn = fv * cv + iv * zv; \
    const float nn = fv * nv + iv; \
    const float hn = ov * (cn / nn); \
    const int gb = row0 + wr * 128 + (K) * 16 + l4 * 4 + r_; \
    const size_t idx = (size_t)gb * 2048 + gj; \
    out[idx]            = hn; \
    out[ 8388608 + idx] = cn; \
    out[16777216 + idx] = mn; \
    out[25165824 + idx] = nn; \
  } } while(0)

  #pragma unroll
  for (int k = 0; k < 8; ++k) {
    if (k < 7) ISSUE_ES(k + 1);
    ECOMP(k);
    if (k < 7) { WAITV(0); BAR(); }
  }
#undef X_ALO
#undef X_AHI
#undef X_BLO
#undef X_BHI
#undef RD_A
#undef RD_B
#undef MMQ
#undef TILE
#undef ISSUE_ES
#undef ES0A
#undef ES0B
#undef ES0C
#undef ECOMP
}

extern "C" void kernel_launch(void* const* d_in, const int* in_sizes, int n_in,
                              void* d_out, int out_size, void* d_ws, size_t ws_size,
                              hipStream_t stream) {
  (void)in_sizes; (void)n_in; (void)out_size; (void)ws_size;
  const float* x  = (const float*)d_in[0];
  const float* h  = (const float*)d_in[1];
  const float* c  = (const float*)d_in[2];
  const float* m  = (const float*)d_in[3];
  const float* n  = (const float*)d_in[4];
  const float* Wi = (const float*)d_in[5];
  const float* bi = (const float*)d_in[6];
  const float* Wh = (const float*)d_in[7];
  const float* bh = (const float*)d_in[8];
  float* out = (float*)d_out;

  // workspace (bf16): Wt 8192x1280 | xb 4096x1024 | hb 4096x2048 | hp 4096x8192
  u16* Wt = (u16*)d_ws;
  u16* xb = Wt + (size_t)8192 * 1280;
  u16* hb = xb + (size_t)4096 * 1024;
  u16* hp = hb + (size_t)4096 * 2048;

  hipFuncSetAttribute((const void*)hproj_kernel,
                      hipFuncAttributeMaxDynamicSharedMemorySize, 131072);
  hipFuncSetAttribute((const void*)slstm_main,
                      hipFuncAttributeMaxDynamicSharedMemorySize, 131072);

  cast_bf16_kernel<<<2048, 256, 0, stream>>>(x, xb, 4096 * 1024 / 8);
  cast_bf16_kernel<<<4096, 256, 0, stream>>>(h, hb, 4096 * 2048 / 8);
  pack_w_kernel<<<dim3(128, 20), dim3(64, 16), 0, stream>>>(Wi, Wh, Wt);
  hproj_kernel<<<2048, 512, 131072, stream>>>(hb, Wt, hp);
  slstm_main<<<512, 512, 131072, stream>>>(xb, Wt, hp, bi, bh, c, m, n, out);
}